// Round 8
// baseline (242.523 us; speedup 1.0000x reference)
//
#include <hip/hip_runtime.h>
#include <hip/hip_bf16.h>
#include <cstdint>
#include <cstddef>

#define DMODEL 1024
#define DINNER 2048
#define NSTATE 16
#define DTRANK 64
#define BATCH 2
#define SEQ 1024
#define ROWS (BATCH*SEQ)   // 2048 token rows
#define NCHUNK 32
#define CLEN (SEQ/NCHUNK)  // 32
#define KSPLIT 16          // split-K ways for x_proj GEMM

typedef __attribute__((ext_vector_type(8))) short short8;
typedef __attribute__((ext_vector_type(4))) short short4v;
typedef __attribute__((ext_vector_type(4))) float f32x4;
typedef __attribute__((ext_vector_type(16))) float f32x16;

__device__ __forceinline__ float bf2f(__hip_bfloat16 h){ return __bfloat162float(h); }
__device__ __forceinline__ float sigmoidf_(float x){ return 1.0f/(1.0f + __expf(-x)); }
__device__ __forceinline__ unsigned short f2bfbits(float v){
  __hip_bfloat16 h = __float2bfloat16(v);
  return *(unsigned short*)&h;
}
__device__ __forceinline__ float bfbits2f(unsigned short u){
  unsigned int x = ((unsigned int)u) << 16;
  return *(float*)&x;
}

__device__ __forceinline__ void gld16(const void* g, void* l){
  __builtin_amdgcn_global_load_lds((const __attribute__((address_space(1))) void*)g,
                                   (__attribute__((address_space(3))) void*)l, 16, 0, 0);
}

// ---------------------------------------------------------------------------
// dtype sniffer — separate tiny kernel (R8 lesson).
// ---------------------------------------------------------------------------
__global__ void sniff_k(const unsigned short* __restrict__ xu, int* __restrict__ flag)
{
  int t = threadIdx.x;           // 64 threads
  int cnt = 0;
  for (int i = t; i < 1024; i += 64) {
    unsigned short u = xu[i];
    int e = (u >> 7) & 0xFF;
    if (e >= 0x70 && e <= 0x86) cnt++;
  }
  for (int o = 32; o; o >>= 1) cnt += __shfl_down(cnt, o);
  if (t == 0) *flag = (cnt >= 768) ? 0 : 1;
}

// ---------------------------------------------------------------------------
// Fused canonicalizer, x4 vectorized (validated R10/R11) + zero-init of xdbl.
// ---------------------------------------------------------------------------
struct CvtArgs {
  const void *s0,*s1,*s2,*s3,*s4,*s5,*s6,*s7,*s8,*s9;
  __hip_bfloat16 *xB,*inpB,*xprojB,*dtprojB,*outpB;
  float *cwF,*cbF,*dtbF,*alF,*DF;
  float *xdblZ;
  const int* flag;
};
#define CVT_C1 2097152
#define CVT_C2 6291456
#define CVT_C3 6299648
#define CVT_C4 6301696
#define CVT_C5 6498304
#define CVT_C6 6629376
#define CVT_C7 6631424
#define CVT_C8 6664192
#define CVT_C9 6666240
#define CVT_TOT 8763392
#define CVT_BLOCKS (CVT_TOT/4/256)   // 8558

__device__ __forceinline__ void cvt_read4(const void* s, int j, int fl, float v[4]){
  if (fl) {
    f32x4 t = ((const f32x4*)s)[j>>2];
    v[0]=t.x; v[1]=t.y; v[2]=t.z; v[3]=t.w;
  } else {
    short4v t = *(const short4v*)((const __hip_bfloat16*)s + j);
    v[0]=bfbits2f((unsigned short)t.x); v[1]=bfbits2f((unsigned short)t.y);
    v[2]=bfbits2f((unsigned short)t.z); v[3]=bfbits2f((unsigned short)t.w);
  }
}
__device__ __forceinline__ void cvt_wB(__hip_bfloat16* d, int j, const float v[4]){
  short4v o;
  o.x=(short)f2bfbits(v[0]); o.y=(short)f2bfbits(v[1]);
  o.z=(short)f2bfbits(v[2]); o.w=(short)f2bfbits(v[3]);
  *(short4v*)(d + j) = o;
}
__device__ __forceinline__ void cvt_wF(float* d, int j, const float v[4]){
  f32x4 o = { v[0], v[1], v[2], v[3] };
  *(f32x4*)(d + j) = o;
}

__global__ __launch_bounds__(256)
void convert_all_k(CvtArgs a)
{
  int i4 = blockIdx.x * 256 + threadIdx.x;
  const int fl = *a.flag;

  if (blockIdx.x < 192) {                       // xdbl: 49152 f32x4 exactly
    f32x4 z = {0.f, 0.f, 0.f, 0.f};
    ((f32x4*)a.xdblZ)[i4] = z;
  }

  int i = i4 * 4;
  if (i >= CVT_TOT) return;
  float v[4];
  if (i < CVT_C1)      { cvt_read4(a.s0, i, fl, v);        cvt_wB(a.xB, i, v); }
  else if (i < CVT_C2) { cvt_read4(a.s1, i-CVT_C1, fl, v); cvt_wB(a.inpB, i-CVT_C1, v); }
  else if (i < CVT_C3) { cvt_read4(a.s2, i-CVT_C2, fl, v); cvt_wF(a.cwF, i-CVT_C2, v); }
  else if (i < CVT_C4) { cvt_read4(a.s3, i-CVT_C3, fl, v); cvt_wF(a.cbF, i-CVT_C3, v); }
  else if (i < CVT_C5) { cvt_read4(a.s4, i-CVT_C4, fl, v); cvt_wB(a.xprojB, i-CVT_C4, v); }
  else if (i < CVT_C6) { cvt_read4(a.s5, i-CVT_C5, fl, v); cvt_wB(a.dtprojB, i-CVT_C5, v); }
  else if (i < CVT_C7) { cvt_read4(a.s6, i-CVT_C6, fl, v); cvt_wF(a.dtbF, i-CVT_C6, v); }
  else if (i < CVT_C8) { cvt_read4(a.s7, i-CVT_C7, fl, v); cvt_wF(a.alF, i-CVT_C7, v); }
  else if (i < CVT_C9) { cvt_read4(a.s8, i-CVT_C8, fl, v); cvt_wF(a.DF, i-CVT_C8, v); }
  else                 { cvt_read4(a.s9, i-CVT_C9, fl, v); cvt_wB(a.outpB, i-CVT_C9, v); }
}

// ---------------------------------------------------------------------------
// NT GEMM: XOR-swizzled LDS staging (validated R8/R9), mfma_f32_32x32x16_bf16
// (validated R17), NBUF template BK=64*NBUF (validated neutral R19),
// SWZ XCD remap (validated R21, -1.5us). C/D layout col=lane&31,
// row=(reg&3)+8*(reg>>2)+4*(lane>>5) [m74/m101].
// R16 lesson: NO device-scope fences in the epilogue (107us stall).
// EPI: 3 = dt_proj: A staged from f32 xdbl (stride 96, k<64), softplus->bf16
//      4 = in_proj split: col<2048 -> bf16 xi; col>=2048 -> silu -> bf16
//      5 = split-K atomic into f32 xdbl [row,96] (x_proj)
//      6 = split-K f32 partial -> q[z] (plain stores; reduce_out_k sums)
// ---------------------------------------------------------------------------
template<int EPI, int NBUF, int SWZ>
__global__ __launch_bounds__(256)
void gemm64(const __hip_bfloat16* __restrict__ A,
            const __hip_bfloat16* __restrict__ W,
            int M, int N, int K, int kchunk,
            float* __restrict__ outF,
            __hip_bfloat16* __restrict__ outH,
            __hip_bfloat16* __restrict__ outH2,
            const float* __restrict__ biasF,
            float* __restrict__ q0, float* __restrict__ q1,
            float* __restrict__ q2, float* __restrict__ q3)
{
  __shared__ alignas(16) __hip_bfloat16 As[NBUF][128*64];   // 16 KB each
  __shared__ alignas(16) __hip_bfloat16 Ws[NBUF][128*64];
  const int tid  = threadIdx.x;
  const int lane = tid & 63;
  const int wave = tid >> 6;
  const int wm = wave & 1, wn = wave >> 1;

  int bx = blockIdx.x, by = blockIdx.y, bz = blockIdx.z;
  if (SWZ) {
    const int nx = gridDim.x, ny = gridDim.y;
    const int id  = (blockIdx.z * ny + blockIdx.y) * nx + blockIdx.x;
    const int nwg = nx * ny * gridDim.z;
    const int rid = (id & 7) * (nwg >> 3) + (id >> 3);
    bx = rid % nx;
    const int t2 = rid / nx;
    by = t2 % ny;
    bz = t2 / ny;
  }
  const int row0 = by * 128;
  const int col0 = bx * 128;

  f32x16 acc[2][2] = {};

  int kbeg = 0, kend = K;
  if (EPI == 5 || EPI == 6) { kbeg = bz * kchunk; kend = kbeg + kchunk; }

  const int r32   = lane & 31;
  const int khalf = lane >> 5;
  const int swz   = r32 & 7;

  for (int k0 = kbeg; k0 < kend; k0 += 64*NBUF) {
#pragma unroll
    for (int h = 0; h < NBUF; ++h) {
      if (EPI == 3) {
        const float* Af32 = (const float*)A;
#pragma unroll
        for (int j = 0; j < 4; ++j) {
          int e = tid + j*256;
          int r = e >> 3, g = e & 7;
          int kc = ((g ^ (r & 7)) << 3);
          const float* src = Af32 + (size_t)(row0 + r) * 96 + kc;
          f32x4 v0 = *(const f32x4*)(src);
          f32x4 v1 = *(const f32x4*)(src + 4);
          short8 o;
          o[0]=(short)f2bfbits(v0.x); o[1]=(short)f2bfbits(v0.y);
          o[2]=(short)f2bfbits(v0.z); o[3]=(short)f2bfbits(v0.w);
          o[4]=(short)f2bfbits(v1.x); o[5]=(short)f2bfbits(v1.y);
          o[6]=(short)f2bfbits(v1.z); o[7]=(short)f2bfbits(v1.w);
          *(short8*)((char*)As[h] + (size_t)e*16) = o;
        }
      } else {
#pragma unroll
        for (int j = 0; j < 4; ++j) {             // A tile, half h
          int e = tid + j*256;
          int r = e >> 3, g = e & 7;
          int kc = ((g ^ (r & 7)) << 3);
          gld16(A + (size_t)(row0 + r) * K + k0 + h*64 + kc, (char*)As[h] + (size_t)e*16);
        }
      }
#pragma unroll
      for (int j = 0; j < 4; ++j) {             // W tile, half h
        int e = tid + j*256;
        int r = e >> 3, g = e & 7;
        int kc = ((g ^ (r & 7)) << 3);
        int rw = col0 + r; if (EPI == 5 && rw > N-1) rw = N-1;
        gld16(W + (size_t)rw * K + k0 + h*64 + kc, (char*)Ws[h] + (size_t)e*16);
      }
    }
    __syncthreads();

#pragma unroll
    for (int h = 0; h < NBUF; ++h) {
      const char* Ab = (const char*)As[h] + ((wm*64 + r32) * 128);
      const char* Wb = (const char*)Ws[h] + ((wn*64 + r32) * 128);
#pragma unroll
      for (int ks = 0; ks < 4; ++ks) {
        const int sx = (((ks*2 + khalf) ^ swz) * 16);
        short8 a0 = *(const short8*)(Ab + sx);
        short8 a1 = *(const short8*)(Ab + 32*128 + sx);
        short8 w0 = *(const short8*)(Wb + sx);
        short8 w1 = *(const short8*)(Wb + 32*128 + sx);
        acc[0][0] = __builtin_amdgcn_mfma_f32_32x32x16_bf16(a0, w0, acc[0][0], 0, 0, 0);
        acc[0][1] = __builtin_amdgcn_mfma_f32_32x32x16_bf16(a0, w1, acc[0][1], 0, 0, 0);
        acc[1][0] = __builtin_amdgcn_mfma_f32_32x32x16_bf16(a1, w0, acc[1][0], 0, 0, 0);
        acc[1][1] = __builtin_amdgcn_mfma_f32_32x32x16_bf16(a1, w1, acc[1][1], 0, 0, 0);
      }
    }
    __syncthreads();
  }

  // C/D layout (m74/m101): col = lane&31, row = (reg&3) + 8*(reg>>2) + 4*(lane>>5)
  const int mbase = row0 + wm*64 + 4*khalf;
  const int nbase = col0 + wn*64 + r32;

  float bv[2];
  if (EPI == 3) { bv[0] = biasF[nbase]; bv[1] = biasF[nbase + 32]; }
  float* qz = nullptr;
  if (EPI == 6) qz = (bz == 0) ? q0 : (bz == 1) ? q1
                   : (bz == 2) ? q2 : q3;

#pragma unroll
  for (int mt = 0; mt < 2; ++mt) {
#pragma unroll
    for (int nt = 0; nt < 2; ++nt) {
#pragma unroll
      for (int r = 0; r < 16; ++r) {
        int row = mbase + mt*32 + (r & 3) + 8*(r >> 2);
        int col = nbase + nt*32;
        float v = acc[mt][nt][r];
        if (EPI == 3) {
          v += bv[nt];
          float sp = fmaxf(v, 0.0f) + __logf(1.0f + __expf(-fabsf(v)));
          outH[(size_t)row * DINNER + col] = __float2bfloat16(sp);
        } else if (EPI == 4) {
          if (col < DINNER) {
            outH[(size_t)row * DINNER + col] = __float2bfloat16(v);
          } else {
            outH2[(size_t)row * DINNER + (col - DINNER)] = __float2bfloat16(v * sigmoidf_(v));
          }
        } else if (EPI == 5) {
          if (col < 96)
            unsafeAtomicAdd(&outF[(size_t)row * 96 + col], v);
        } else if (EPI == 6) {
          qz[(size_t)row * DMODEL + col] = v;
        }
      }
    }
  }
}

// ---------------------------------------------------------------------------
// out_proj split-K reduce: out = q0+q1+q2+q3, f32x4 vectorized
// ---------------------------------------------------------------------------
__global__ __launch_bounds__(256)
void reduce_out_k(const float* __restrict__ q0, const float* __restrict__ q1,
                  const float* __restrict__ q2, const float* __restrict__ q3,
                  float* __restrict__ out)
{
  int i4 = blockIdx.x * 256 + threadIdx.x;     // ROWS*DMODEL/4 = 524288
  if (i4 >= ROWS*DMODEL/4) return;
  f32x4 a = ((const f32x4*)q0)[i4];
  f32x4 b = ((const f32x4*)q1)[i4];
  f32x4 c = ((const f32x4*)q2)[i4];
  f32x4 d = ((const f32x4*)q3)[i4];
  f32x4 o = { (a.x+b.x)+(c.x+d.x), (a.y+b.y)+(c.y+d.y),
              (a.z+b.z)+(c.z+d.z), (a.w+b.w)+(c.w+d.w) };
  ((f32x4*)out)[i4] = o;
}

// ---------------------------------------------------------------------------
// Depthwise causal conv + bias + SiLU, x4 vectorized (validated R12).
// ---------------------------------------------------------------------------
__global__ __launch_bounds__(256)
void conv_silu_k(const __hip_bfloat16* __restrict__ xi,
                 const float* __restrict__ cw,
                 const float* __restrict__ cb,
                 __hip_bfloat16* __restrict__ xcH)
{
  int idx4 = blockIdx.x * 256 + threadIdx.x;   // ROWS*DINNER/4 threads
  int idx  = idx4 * 4;
  int d  = idx & (DINNER - 1);
  int t  = (idx >> 11) & (SEQ - 1);
  int bt = idx >> 11;

  f32x4 cb4 = *(const f32x4*)&cb[d];
  float a0=cb4.x, a1=cb4.y, a2=cb4.z, a3=cb4.w;
  f32x4 w0 = *(const f32x4*)&cw[(d+0)*4];
  f32x4 w1 = *(const f32x4*)&cw[(d+1)*4];
  f32x4 w2 = *(const f32x4*)&cw[(d+2)*4];
  f32x4 w3 = *(const f32x4*)&cw[(d+3)*4];

#pragma unroll
  for (int i = 0; i < 4; ++i) {
    if (t - 3 + i >= 0) {
      short4v xv = *(const short4v*)(xi + (size_t)(bt - 3 + i) * DINNER + d);
      float x0 = bfbits2f((unsigned short)xv.x);
      float x1 = bfbits2f((unsigned short)xv.y);
      float x2 = bfbits2f((unsigned short)xv.z);
      float x3 = bfbits2f((unsigned short)xv.w);
      float c0 = (i==0)?w0.x:(i==1)?w0.y:(i==2)?w0.z:w0.w;
      float c1 = (i==0)?w1.x:(i==1)?w1.y:(i==2)?w1.z:w1.w;
      float c2 = (i==0)?w2.x:(i==1)?w2.y:(i==2)?w2.z:w2.w;
      float c3 = (i==0)?w3.x:(i==1)?w3.y:(i==2)?w3.z:w3.w;
      a0 += c0*x0; a1 += c1*x1; a2 += c2*x2; a3 += c3*x3;
    }
  }
  float y0 = a0 * sigmoidf_(a0);
  float y1 = a1 * sigmoidf_(a1);
  float y2 = a2 * sigmoidf_(a2);
  float y3 = a3 * sigmoidf_(a3);
  short4v o;
  o.x=(short)f2bfbits(y0); o.y=(short)f2bfbits(y1);
  o.z=(short)f2bfbits(y2); o.w=(short)f2bfbits(y3);
  *(short4v*)(xcH + idx) = o;
}

// ---------------------------------------------------------------------------
// Chunked selective scan (lane layout validated R7, GSTEP=8 validated R11).
// NCHUNK=32 (CLEN=32): 2048 blocks = 8 blocks/CU. delta bf16 (validated R18).
// R22: coalesced LDS staging of the per-block [32t x 64ch] delta/xc tiles —
// replaces ~64-96 scattered 2B global loads per thread (4KB stride, 4x
// quad-redundant) with ONE short8 load per thread per array. Scan reads raw
// bf16 bits from LDS ([t][ch] layout: staging is a direct b128 copy; reads
// are <=2-way bank aliased = free, m136). Bit-identical values.
// ---------------------------------------------------------------------------
#define GSTEP 8

__global__ __launch_bounds__(256)
void stats_k(const __hip_bfloat16* __restrict__ delta,
             const __hip_bfloat16* __restrict__ xcH,
             const float* __restrict__ xdbl,
             const float* __restrict__ alF,
             float* __restrict__ Hc, float* __restrict__ Sd)
{
  __shared__ alignas(16) float Bs[CLEN*16];             // 2 KB
  __shared__ alignas(16) unsigned short dS[CLEN*64];    // 4 KB
  __shared__ alignas(16) unsigned short xS[CLEN*64];    // 4 KB
  const int bid  = blockIdx.x;                  // b*1024 + c*32 + cg
  const int b    = bid >> 10;
  const int c    = (bid >> 5) & (NCHUNK-1);
  const int cg   = bid & 31;
  const int tid  = threadIdx.x;
  const int lane = tid & 63;
  const int wave = tid >> 6;
  const int sub  = lane & 3;
  const int chL  = (wave << 4) + (lane >> 2);   // 0..63 within block
  const int ch   = (cg << 6) + chL;

  const size_t rb = (size_t)b * SEQ + (size_t)c * CLEN;

  {  // coalesced tile stage: exactly one b128 per thread per array
    int t = tid >> 3, g = (tid & 7) * 8;
    *(short8*)&dS[t*64 + g] = *(const short8*)(delta + (rb + t)*DINNER + (cg<<6) + g);
    *(short8*)&xS[t*64 + g] = *(const short8*)(xcH   + (rb + t)*DINNER + (cg<<6) + g);
  }
  for (int i = tid; i < CLEN*16; i += 256) {
    int t = i >> 4, j = i & 15;
    Bs[i] = xdbl[(rb + t)*96 + 64 + j];
  }
  __syncthreads();

  float negA[4];
#pragma unroll
  for (int j = 0; j < 4; ++j) negA[j] = -__expf(alF[ch*NSTATE + sub*4 + j]);

  float h0=0.f,h1=0.f,h2=0.f,h3=0.f, sd=0.f;
  float d0[GSTEP], x0[GSTEP], d1[GSTEP], x1[GSTEP];

#define PF1(D_,X_,T0) \
  _Pragma("unroll") \
  for (int u = 0; u < GSTEP; ++u) { \
    D_[u] = bfbits2f(dS[((T0)+u)*64 + chL]); \
    X_[u] = bfbits2f(xS[((T0)+u)*64 + chL]); \
  }
#define ST1(D_,X_,T0) \
  _Pragma("unroll") \
  for (int u = 0; u < GSTEP; ++u) { \
    float d_ = D_[u]; \
    sd += d_; \
    float du = d_ * X_[u]; \
    f32x4 B4 = *(const f32x4*)&Bs[((T0)+u)*16 + sub*4]; \
    h0 = __expf(d_*negA[0])*h0 + du*B4.x; \
    h1 = __expf(d_*negA[1])*h1 + du*B4.y; \
    h2 = __expf(d_*negA[2])*h2 + du*B4.z; \
    h3 = __expf(d_*negA[3])*h3 + du*B4.w; \
  }

  PF1(d0, x0, 0)
  for (int t0 = 0; t0 < CLEN; t0 += 2*GSTEP) {
    PF1(d1, x1, t0 + GSTEP)
    ST1(d0, x0, t0)
    if (t0 + 2*GSTEP < CLEN) { PF1(d0, x0, t0 + 2*GSTEP) }
    ST1(d1, x1, t0 + GSTEP)
  }
#undef PF1
#undef ST1

  const size_t bc = (size_t)(b*NCHUNK + c);
  f32x4 hv = { h0, h1, h2, h3 };
  *(f32x4*)&Hc[(bc*DINNER + ch)*NSTATE + sub*4] = hv;
  if (sub == 0) Sd[bc*DINNER + ch] = sd;
}

__global__ __launch_bounds__(256)
void carry_k(const float* __restrict__ Hc, const float* __restrict__ Sd,
             const float* __restrict__ alF, float* __restrict__ hin)
{
  int i = blockIdx.x * 256 + threadIdx.x;       // BATCH*DINNER*NSTATE = 65536
  int n  = i & (NSTATE-1);
  int ch = (i >> 4) & (DINNER-1);
  int b  = i >> 15;
  float negA = -__expf(alF[ch * NSTATE + n]);
  float h = 0.f;
#pragma unroll
  for (int c = 0; c < NCHUNK; ++c) {
    size_t bc = (size_t)(b*NCHUNK + c);
    hin[(bc*DINNER + ch)*NSTATE + n] = h;
    float P = __expf(negA * Sd[bc*DINNER + ch]);
    h = P * h + Hc[(bc*DINNER + ch)*NSTATE + n];
  }
}

__global__ __launch_bounds__(256)
void emit_k(const __hip_bfloat16* __restrict__ delta,
            const __hip_bfloat16* __restrict__ xcH,
            const float* __restrict__ xdbl,
            const __hip_bfloat16* __restrict__ zsH,
            const float* __restrict__ alF,
            const float* __restrict__ DF,
            const float* __restrict__ hin,
            __hip_bfloat16* __restrict__ yH)
{
  __shared__ alignas(16) float BCs[CLEN*32];            // 4 KB
  __shared__ alignas(16) unsigned short dS[CLEN*64];    // 4 KB
  __shared__ alignas(16) unsigned short xS[CLEN*64];    // 4 KB
  __shared__ alignas(16) unsigned short yS[CLEN*72];    // 4.5 KB (72 = 64+8 pad)
  const int bid  = blockIdx.x;
  const int b    = bid >> 10;
  const int c    = (bid >> 5) & (NCHUNK-1);
  const int cg   = bid & 31;
  const int tid  = threadIdx.x;
  const int lane = tid & 63;
  const int wave = tid >> 6;
  const int sub  = lane & 3;
  const int chL  = (wave << 4) + (lane >> 2);   // 0..63 within block
  const int ch   = (cg << 6) + chL;

  const size_t rb = (size_t)b * SEQ + (size_t)c * CLEN;

  {  // coalesced tile stage: one b128 per thread per array
    int t = tid >> 3, g = (tid & 7) * 8;
    *(short8*)&dS[t*64 + g] = *(const short8*)(delta + (rb + t)*DINNER + (cg<<6) + g);
    *(short8*)&xS[t*64 + g] = *(const short8*)(xcH   + (rb + t)*DINNER + (cg<<6) + g);
  }
  for (int i = tid; i < CLEN*32; i += 256) {
    int t = i >> 5, j = i & 31;
    BCs[i] = xdbl[(rb + t)*96 + 64 + j];
  }
  __syncthreads();

  float negA[4];
#pragma unroll
  for (int j = 0; j < 4; ++j) negA[j] = -__expf(alF[ch*NSTATE + sub*4 + j]);
  const float Dch = DF[ch];

  const __hip_bfloat16* zp = zsH + rb * DINNER + ch;

  f32x4 hv = *(const f32x4*)&hin[((size_t)(b*NCHUNK + c)*DINNER + ch)*NSTATE + sub*4];
  float h0=hv.x, h1=hv.y, h2=hv.z, h3=hv.w;

  float d0[GSTEP], x0[GSTEP], z0[GSTEP], d1[GSTEP], x1[GSTEP], z1[GSTEP];

  // z is consumed only by sub==0 lanes: exec-masked direct load (removes the
  // 4x quad-redundant broadcast of the old path).
#define PF(D_,X_,Z_,T0) \
  _Pragma("unroll") \
  for (int u = 0; u < GSTEP; ++u) { \
    D_[u] = bfbits2f(dS[((T0)+u)*64 + chL]); \
    X_[u] = bfbits2f(xS[((T0)+u)*64 + chL]); \
    Z_[u] = 0.f; \
    if (sub == 0) Z_[u] = bf2f(zp[(size_t)((T0)+u) * DINNER]); \
  }
#define STEPS(D_,X_,Z_,T0) \
  _Pragma("unroll") \
  for (int u = 0; u < GSTEP; ++u) { \
    float d_ = D_[u]; \
    float du = d_ * X_[u]; \
    f32x4 B4 = *(const f32x4*)&BCs[((T0)+u)*32 + sub*4]; \
    f32x4 C4 = *(const f32x4*)&BCs[((T0)+u)*32 + 16 + sub*4]; \
    h0 = __expf(d_*negA[0])*h0 + du*B4.x; \
    h1 = __expf(d_*negA[1])*h1 + du*B4.y; \
    h2 = __expf(d_*negA[2])*h2 + du*B4.z; \
    h3 = __expf(d_*negA[3])*h3 + du*B4.w; \
    float p = h0*C4.x + h1*C4.y + h2*C4.z + h3*C4.w; \
    p += __shfl_xor(p, 1); \
    p += __shfl_xor(p, 2); \
    if (sub == 0) { \
      float y = (p + X_[u] * Dch) * Z_[u]; \
      yS[((T0)+u)*72 + chL] = f2bfbits(y); \
    } \
  }

  PF(d0, x0, z0, 0)
  for (int t0 = 0; t0 < CLEN; t0 += 2*GSTEP) {
    PF(d1, x1, z1, t0 + GSTEP)
    STEPS(d0, x0, z0, t0)
    if (t0 + 2*GSTEP < CLEN) { PF(d0, x0, z0, t0 + 2*GSTEP) }
    STEPS(d1, x1, z1, t0 + GSTEP)
  }
#undef PF
#undef STEPS

  // coalesced y flush: 256 threads x 16B = 4 KB slab (32 t x 64 ch)
  __syncthreads();
  {
    int t2 = tid >> 3, p2 = tid & 7;
    short8 v = *(const short8*)&yS[t2*72 + p2*8];
    *(short8*)(yH + (rb + t2)*DINNER + (cg << 6) + p2*8) = v;
  }
}

// ---------------------------------------------------------------------------
extern "C" void kernel_launch(void* const* d_in, const int* in_sizes, int n_in,
                              void* d_out, int out_size, void* d_ws, size_t ws_size,
                              hipStream_t stream)
{
  float* out = (float*)d_out;   // reference output dtype: float32
  char* ws = (char*)d_ws;
  const size_t MB = 1024*1024;

  // workspace layout (84 MB, liveness-aliased; ws_size = 256 MB)
  // scalar region offsets: VALIDATED R13 layout — do not renumber.
  int*            flag    = (int*)            (ws);
  float*          cwF     = (float*)          (ws + 1024);
  float*          cbF     = (float*)          (ws + 40*1024);
  float*          dtbF    = (float*)          (ws + 56*1024);
  float*          alF     = (float*)          (ws + 72*1024);
  float*          DF      = (float*)          (ws + 208*1024);
  float*          Sd      = (float*)          (ws + 256*1024);      // 512 KB (NCHUNK=32)
  __hip_bfloat16* xB      = (__hip_bfloat16*) (ws + 1*MB);          // 4 MB  (dead after G1)
  __hip_bfloat16* inpB    = (__hip_bfloat16*) (ws + 5*MB);          // 8 MB
  __hip_bfloat16* xiB     = (__hip_bfloat16*) (ws + 13*MB);         // 8 MB  (dead after conv)
  __hip_bfloat16* dltH    = (__hip_bfloat16*) (ws + 1*MB);          // 8 MB bf16 delta, aliases xB/inpB[:4MB]
  __hip_bfloat16* xprojB  = (__hip_bfloat16*) (ws + 21*MB);
  __hip_bfloat16* dtprojB = (__hip_bfloat16*) (ws + 21*MB + 512*1024);
  __hip_bfloat16* outpB   = (__hip_bfloat16*) (ws + 22*MB);         // 4 MB
  __hip_bfloat16* zsH     = (__hip_bfloat16*) (ws + 26*MB);         // 8 MB (bf16 silu(z))
  __hip_bfloat16* xcH     = (__hip_bfloat16*) (ws + 42*MB);         // 8 MB
  float*          xdbl    = (float*)          (ws + 50*MB);         // 768 KB
  __hip_bfloat16* yH      = (__hip_bfloat16*) (ws + 52*MB);         // 8 MB (live into out_proj)
  float*          Hc      = (float*)          (ws + 68*MB);         // 8 MB (NCHUNK=32)
  float*          hin     = (float*)          (ws + 76*MB);         // 8 MB -> top 84 MB
  // out_proj f32 partials (8 MB each), regions dead after emit_k:
  float*          q0      = (float*)          (ws + 1*MB);          // dltH (dead)
  float*          q1      = (float*)          (ws + 9*MB);          // xiB lo (dead)
  float*          q2      = (float*)          (ws + 26*MB);         // zsH (dead)
  float*          q3      = (float*)          (ws + 34*MB);         // free

  dim3 blk(256);

  // 0) sniff (1 tiny block) + vectorized canonicalize (+ xdbl zero-init)
  sniff_k<<<1, 64, 0, stream>>>((const unsigned short*)d_in[0], flag);
  CvtArgs ca = { d_in[0], d_in[1], d_in[2], d_in[3], d_in[4],
                 d_in[5], d_in[6], d_in[7], d_in[8], d_in[9],
                 xB, inpB, xprojB, dtprojB, outpB,
                 cwF, cbF, dtbF, alF, DF, xdbl, flag };
  convert_all_k<<<CVT_BLOCKS, blk, 0, stream>>>(ca);

  // 1) in_proj (2048 x 4096 x 1024): BK=128, XCD-swizzled, split -> xi, silu(z)
  gemm64<4,2,1><<<dim3(4096/128, ROWS/128), blk, 0, stream>>>(
      xB, inpB, ROWS, 2*DINNER, DMODEL, 0, nullptr, xiB, zsH, nullptr,
      nullptr, nullptr, nullptr, nullptr);

  // 2) xc = silu(depthwise_conv(xi) + b), x4 vectorized
  conv_silu_k<<<(ROWS*DINNER/4)/256, blk, 0, stream>>>(xiB, cwF, cbF, xcH);

  // 3) x_dbl (2048 x 96 x 2048): 16-way split-K (kchunk=128), atomic into xdbl
  gemm64<5,2,0><<<dim3(1, ROWS/128, KSPLIT), blk, 0, stream>>>(
      xcH, xprojB, ROWS, 96, DINNER, DINNER/KSPLIT, xdbl, nullptr, nullptr, nullptr,
      nullptr, nullptr, nullptr, nullptr);

  // 4) delta = softplus(dt @ dt_proj^T + dt_b) (2048 x 2048 x 64):
  //    A staged directly from f32 xdbl (fused dt conversion), output bf16.
  gemm64<3,1,0><<<dim3(DINNER/128, ROWS/128), blk, 0, stream>>>(
      (const __hip_bfloat16*)xdbl, dtprojB, ROWS, DINNER, DTRANK, 0,
      nullptr, dltH, nullptr, dtbF,
      nullptr, nullptr, nullptr, nullptr);

  // 5) chunked selective scan (NCHUNK=32) + fused combine -> bf16 yH
  stats_k<<<BATCH*NCHUNK*32, blk, 0, stream>>>(dltH, xcH, xdbl, alF, Hc, Sd);
  carry_k<<<(BATCH*DINNER*NSTATE)/256, blk, 0, stream>>>(Hc, Sd, alF, hin);
  emit_k<<<BATCH*NCHUNK*32, blk, 0, stream>>>(dltH, xcH, xdbl, zsH, alF, DF, hin, yH);

  // 6) out_proj (2048 x 1024 x 2048): BK=128, XCD-swizzled, split-K=4 + reduce
  gemm64<6,2,1><<<dim3(DMODEL/128, ROWS/128, 4), blk, 0, stream>>>(
      yH, outpB, ROWS, DMODEL, DINNER, DINNER/4, nullptr, nullptr, nullptr, nullptr,
      q0, q1, q2, q3);
  reduce_out_k<<<(ROWS*DMODEL/4)/256, blk, 0, stream>>>(q0, q1, q2, q3, out);
}

// Round 9
// 228.708 us; speedup vs baseline: 1.0604x; 1.0604x over previous
//
#include <hip/hip_runtime.h>
#include <hip/hip_bf16.h>
#include <cstdint>
#include <cstddef>

#define DMODEL 1024
#define DINNER 2048
#define NSTATE 16
#define DTRANK 64
#define BATCH 2
#define SEQ 1024
#define ROWS (BATCH*SEQ)   // 2048 token rows
#define NCHUNK 64
#define CLEN (SEQ/NCHUNK)  // 16
#define KSPLIT 16          // split-K ways for x_proj GEMM

typedef __attribute__((ext_vector_type(8))) short short8;
typedef __attribute__((ext_vector_type(4))) short short4v;
typedef __attribute__((ext_vector_type(4))) float f32x4;
typedef __attribute__((ext_vector_type(16))) float f32x16;

__device__ __forceinline__ float bf2f(__hip_bfloat16 h){ return __bfloat162float(h); }
__device__ __forceinline__ float sigmoidf_(float x){ return 1.0f/(1.0f + __expf(-x)); }
__device__ __forceinline__ unsigned short f2bfbits(float v){
  __hip_bfloat16 h = __float2bfloat16(v);
  return *(unsigned short*)&h;
}
__device__ __forceinline__ float bfbits2f(unsigned short u){
  unsigned int x = ((unsigned int)u) << 16;
  return *(float*)&x;
}

__device__ __forceinline__ void gld16(const void* g, void* l){
  __builtin_amdgcn_global_load_lds((const __attribute__((address_space(1))) void*)g,
                                   (__attribute__((address_space(3))) void*)l, 16, 0, 0);
}

// ---------------------------------------------------------------------------
// dtype sniffer — separate tiny kernel (R8 lesson).
// ---------------------------------------------------------------------------
__global__ void sniff_k(const unsigned short* __restrict__ xu, int* __restrict__ flag)
{
  int t = threadIdx.x;           // 64 threads
  int cnt = 0;
  for (int i = t; i < 1024; i += 64) {
    unsigned short u = xu[i];
    int e = (u >> 7) & 0xFF;
    if (e >= 0x70 && e <= 0x86) cnt++;
  }
  for (int o = 32; o; o >>= 1) cnt += __shfl_down(cnt, o);
  if (t == 0) *flag = (cnt >= 768) ? 0 : 1;
}

// ---------------------------------------------------------------------------
// Fused canonicalizer, x4 vectorized (validated R10/R11) + zero-init of xdbl.
// ---------------------------------------------------------------------------
struct CvtArgs {
  const void *s0,*s1,*s2,*s3,*s4,*s5,*s6,*s7,*s8,*s9;
  __hip_bfloat16 *xB,*inpB,*xprojB,*dtprojB,*outpB;
  float *cwF,*cbF,*dtbF,*alF,*DF;
  float *xdblZ;
  const int* flag;
};
#define CVT_C1 2097152
#define CVT_C2 6291456
#define CVT_C3 6299648
#define CVT_C4 6301696
#define CVT_C5 6498304
#define CVT_C6 6629376
#define CVT_C7 6631424
#define CVT_C8 6664192
#define CVT_C9 6666240
#define CVT_TOT 8763392
#define CVT_BLOCKS (CVT_TOT/4/256)   // 8558

__device__ __forceinline__ void cvt_read4(const void* s, int j, int fl, float v[4]){
  if (fl) {
    f32x4 t = ((const f32x4*)s)[j>>2];
    v[0]=t.x; v[1]=t.y; v[2]=t.z; v[3]=t.w;
  } else {
    short4v t = *(const short4v*)((const __hip_bfloat16*)s + j);
    v[0]=bfbits2f((unsigned short)t.x); v[1]=bfbits2f((unsigned short)t.y);
    v[2]=bfbits2f((unsigned short)t.z); v[3]=bfbits2f((unsigned short)t.w);
  }
}
__device__ __forceinline__ void cvt_wB(__hip_bfloat16* d, int j, const float v[4]){
  short4v o;
  o.x=(short)f2bfbits(v[0]); o.y=(short)f2bfbits(v[1]);
  o.z=(short)f2bfbits(v[2]); o.w=(short)f2bfbits(v[3]);
  *(short4v*)(d + j) = o;
}
__device__ __forceinline__ void cvt_wF(float* d, int j, const float v[4]){
  f32x4 o = { v[0], v[1], v[2], v[3] };
  *(f32x4*)(d + j) = o;
}

__global__ __launch_bounds__(256)
void convert_all_k(CvtArgs a)
{
  int i4 = blockIdx.x * 256 + threadIdx.x;
  const int fl = *a.flag;

  if (blockIdx.x < 192) {                       // xdbl: 49152 f32x4 exactly
    f32x4 z = {0.f, 0.f, 0.f, 0.f};
    ((f32x4*)a.xdblZ)[i4] = z;
  }

  int i = i4 * 4;
  if (i >= CVT_TOT) return;
  float v[4];
  if (i < CVT_C1)      { cvt_read4(a.s0, i, fl, v);        cvt_wB(a.xB, i, v); }
  else if (i < CVT_C2) { cvt_read4(a.s1, i-CVT_C1, fl, v); cvt_wB(a.inpB, i-CVT_C1, v); }
  else if (i < CVT_C3) { cvt_read4(a.s2, i-CVT_C2, fl, v); cvt_wF(a.cwF, i-CVT_C2, v); }
  else if (i < CVT_C4) { cvt_read4(a.s3, i-CVT_C3, fl, v); cvt_wF(a.cbF, i-CVT_C3, v); }
  else if (i < CVT_C5) { cvt_read4(a.s4, i-CVT_C4, fl, v); cvt_wB(a.xprojB, i-CVT_C4, v); }
  else if (i < CVT_C6) { cvt_read4(a.s5, i-CVT_C5, fl, v); cvt_wB(a.dtprojB, i-CVT_C5, v); }
  else if (i < CVT_C7) { cvt_read4(a.s6, i-CVT_C6, fl, v); cvt_wF(a.dtbF, i-CVT_C6, v); }
  else if (i < CVT_C8) { cvt_read4(a.s7, i-CVT_C7, fl, v); cvt_wF(a.alF, i-CVT_C7, v); }
  else if (i < CVT_C9) { cvt_read4(a.s8, i-CVT_C8, fl, v); cvt_wF(a.DF, i-CVT_C8, v); }
  else                 { cvt_read4(a.s9, i-CVT_C9, fl, v); cvt_wB(a.outpB, i-CVT_C9, v); }
}

// ---------------------------------------------------------------------------
// NT GEMM: XOR-swizzled LDS staging (validated R8/R9), mfma_f32_32x32x16_bf16
// (validated R17), NBUF template BK=64*NBUF (validated neutral R19),
// SWZ XCD remap (validated R21, -1.5us). C/D layout col=lane&31,
// row=(reg&3)+8*(reg>>2)+4*(lane>>5) [m74/m101].
// R16 lesson: NO device-scope fences in the epilogue (107us stall).
// EPI: 3 = dt_proj: A staged from f32 xdbl (stride 96, k<64), softplus->bf16
//      4 = in_proj split: col<2048 -> bf16 xi; col>=2048 -> silu -> bf16
//      5 = split-K atomic into f32 xdbl [row,96] (x_proj)
//      6 = split-K f32 partial -> q[z] (plain stores; reduce_out_k sums)
// ---------------------------------------------------------------------------
template<int EPI, int NBUF, int SWZ>
__global__ __launch_bounds__(256)
void gemm64(const __hip_bfloat16* __restrict__ A,
            const __hip_bfloat16* __restrict__ W,
            int M, int N, int K, int kchunk,
            float* __restrict__ outF,
            __hip_bfloat16* __restrict__ outH,
            __hip_bfloat16* __restrict__ outH2,
            const float* __restrict__ biasF,
            float* __restrict__ q0, float* __restrict__ q1,
            float* __restrict__ q2, float* __restrict__ q3)
{
  __shared__ alignas(16) __hip_bfloat16 As[NBUF][128*64];   // 16 KB each
  __shared__ alignas(16) __hip_bfloat16 Ws[NBUF][128*64];
  const int tid  = threadIdx.x;
  const int lane = tid & 63;
  const int wave = tid >> 6;
  const int wm = wave & 1, wn = wave >> 1;

  int bx = blockIdx.x, by = blockIdx.y, bz = blockIdx.z;
  if (SWZ) {
    const int nx = gridDim.x, ny = gridDim.y;
    const int id  = (blockIdx.z * ny + blockIdx.y) * nx + blockIdx.x;
    const int nwg = nx * ny * gridDim.z;
    const int rid = (id & 7) * (nwg >> 3) + (id >> 3);
    bx = rid % nx;
    const int t2 = rid / nx;
    by = t2 % ny;
    bz = t2 / ny;
  }
  const int row0 = by * 128;
  const int col0 = bx * 128;

  f32x16 acc[2][2] = {};

  int kbeg = 0, kend = K;
  if (EPI == 5 || EPI == 6) { kbeg = bz * kchunk; kend = kbeg + kchunk; }

  const int r32   = lane & 31;
  const int khalf = lane >> 5;
  const int swz   = r32 & 7;

  for (int k0 = kbeg; k0 < kend; k0 += 64*NBUF) {
#pragma unroll
    for (int h = 0; h < NBUF; ++h) {
      if (EPI == 3) {
        const float* Af32 = (const float*)A;
#pragma unroll
        for (int j = 0; j < 4; ++j) {
          int e = tid + j*256;
          int r = e >> 3, g = e & 7;
          int kc = ((g ^ (r & 7)) << 3);
          const float* src = Af32 + (size_t)(row0 + r) * 96 + kc;
          f32x4 v0 = *(const f32x4*)(src);
          f32x4 v1 = *(const f32x4*)(src + 4);
          short8 o;
          o[0]=(short)f2bfbits(v0.x); o[1]=(short)f2bfbits(v0.y);
          o[2]=(short)f2bfbits(v0.z); o[3]=(short)f2bfbits(v0.w);
          o[4]=(short)f2bfbits(v1.x); o[5]=(short)f2bfbits(v1.y);
          o[6]=(short)f2bfbits(v1.z); o[7]=(short)f2bfbits(v1.w);
          *(short8*)((char*)As[h] + (size_t)e*16) = o;
        }
      } else {
#pragma unroll
        for (int j = 0; j < 4; ++j) {             // A tile, half h
          int e = tid + j*256;
          int r = e >> 3, g = e & 7;
          int kc = ((g ^ (r & 7)) << 3);
          gld16(A + (size_t)(row0 + r) * K + k0 + h*64 + kc, (char*)As[h] + (size_t)e*16);
        }
      }
#pragma unroll
      for (int j = 0; j < 4; ++j) {             // W tile, half h
        int e = tid + j*256;
        int r = e >> 3, g = e & 7;
        int kc = ((g ^ (r & 7)) << 3);
        int rw = col0 + r; if (EPI == 5 && rw > N-1) rw = N-1;
        gld16(W + (size_t)rw * K + k0 + h*64 + kc, (char*)Ws[h] + (size_t)e*16);
      }
    }
    __syncthreads();

#pragma unroll
    for (int h = 0; h < NBUF; ++h) {
      const char* Ab = (const char*)As[h] + ((wm*64 + r32) * 128);
      const char* Wb = (const char*)Ws[h] + ((wn*64 + r32) * 128);
#pragma unroll
      for (int ks = 0; ks < 4; ++ks) {
        const int sx = (((ks*2 + khalf) ^ swz) * 16);
        short8 a0 = *(const short8*)(Ab + sx);
        short8 a1 = *(const short8*)(Ab + 32*128 + sx);
        short8 w0 = *(const short8*)(Wb + sx);
        short8 w1 = *(const short8*)(Wb + 32*128 + sx);
        acc[0][0] = __builtin_amdgcn_mfma_f32_32x32x16_bf16(a0, w0, acc[0][0], 0, 0, 0);
        acc[0][1] = __builtin_amdgcn_mfma_f32_32x32x16_bf16(a0, w1, acc[0][1], 0, 0, 0);
        acc[1][0] = __builtin_amdgcn_mfma_f32_32x32x16_bf16(a1, w0, acc[1][0], 0, 0, 0);
        acc[1][1] = __builtin_amdgcn_mfma_f32_32x32x16_bf16(a1, w1, acc[1][1], 0, 0, 0);
      }
    }
    __syncthreads();
  }

  // C/D layout (m74/m101): col = lane&31, row = (reg&3) + 8*(reg>>2) + 4*(lane>>5)
  const int mbase = row0 + wm*64 + 4*khalf;
  const int nbase = col0 + wn*64 + r32;

  float bv[2];
  if (EPI == 3) { bv[0] = biasF[nbase]; bv[1] = biasF[nbase + 32]; }
  float* qz = nullptr;
  if (EPI == 6) qz = (bz == 0) ? q0 : (bz == 1) ? q1
                   : (bz == 2) ? q2 : q3;

#pragma unroll
  for (int mt = 0; mt < 2; ++mt) {
#pragma unroll
    for (int nt = 0; nt < 2; ++nt) {
#pragma unroll
      for (int r = 0; r < 16; ++r) {
        int row = mbase + mt*32 + (r & 3) + 8*(r >> 2);
        int col = nbase + nt*32;
        float v = acc[mt][nt][r];
        if (EPI == 3) {
          v += bv[nt];
          float sp = fmaxf(v, 0.0f) + __logf(1.0f + __expf(-fabsf(v)));
          outH[(size_t)row * DINNER + col] = __float2bfloat16(sp);
        } else if (EPI == 4) {
          if (col < DINNER) {
            outH[(size_t)row * DINNER + col] = __float2bfloat16(v);
          } else {
            outH2[(size_t)row * DINNER + (col - DINNER)] = __float2bfloat16(v * sigmoidf_(v));
          }
        } else if (EPI == 5) {
          if (col < 96)
            unsafeAtomicAdd(&outF[(size_t)row * 96 + col], v);
        } else if (EPI == 6) {
          qz[(size_t)row * DMODEL + col] = v;
        }
      }
    }
  }
}

// ---------------------------------------------------------------------------
// out_proj split-K reduce: out = q0+q1+q2+q3, f32x4 vectorized
// ---------------------------------------------------------------------------
__global__ __launch_bounds__(256)
void reduce_out_k(const float* __restrict__ q0, const float* __restrict__ q1,
                  const float* __restrict__ q2, const float* __restrict__ q3,
                  float* __restrict__ out)
{
  int i4 = blockIdx.x * 256 + threadIdx.x;     // ROWS*DMODEL/4 = 524288
  if (i4 >= ROWS*DMODEL/4) return;
  f32x4 a = ((const f32x4*)q0)[i4];
  f32x4 b = ((const f32x4*)q1)[i4];
  f32x4 c = ((const f32x4*)q2)[i4];
  f32x4 d = ((const f32x4*)q3)[i4];
  f32x4 o = { (a.x+b.x)+(c.x+d.x), (a.y+b.y)+(c.y+d.y),
              (a.z+b.z)+(c.z+d.z), (a.w+b.w)+(c.w+d.w) };
  ((f32x4*)out)[i4] = o;
}

// ---------------------------------------------------------------------------
// Depthwise causal conv + bias + SiLU, x4 vectorized (validated R12).
// ---------------------------------------------------------------------------
__global__ __launch_bounds__(256)
void conv_silu_k(const __hip_bfloat16* __restrict__ xi,
                 const float* __restrict__ cw,
                 const float* __restrict__ cb,
                 __hip_bfloat16* __restrict__ xcH)
{
  int idx4 = blockIdx.x * 256 + threadIdx.x;   // ROWS*DINNER/4 threads
  int idx  = idx4 * 4;
  int d  = idx & (DINNER - 1);
  int t  = (idx >> 11) & (SEQ - 1);
  int bt = idx >> 11;

  f32x4 cb4 = *(const f32x4*)&cb[d];
  float a0=cb4.x, a1=cb4.y, a2=cb4.z, a3=cb4.w;
  f32x4 w0 = *(const f32x4*)&cw[(d+0)*4];
  f32x4 w1 = *(const f32x4*)&cw[(d+1)*4];
  f32x4 w2 = *(const f32x4*)&cw[(d+2)*4];
  f32x4 w3 = *(const f32x4*)&cw[(d+3)*4];

#pragma unroll
  for (int i = 0; i < 4; ++i) {
    if (t - 3 + i >= 0) {
      short4v xv = *(const short4v*)(xi + (size_t)(bt - 3 + i) * DINNER + d);
      float x0 = bfbits2f((unsigned short)xv.x);
      float x1 = bfbits2f((unsigned short)xv.y);
      float x2 = bfbits2f((unsigned short)xv.z);
      float x3 = bfbits2f((unsigned short)xv.w);
      float c0 = (i==0)?w0.x:(i==1)?w0.y:(i==2)?w0.z:w0.w;
      float c1 = (i==0)?w1.x:(i==1)?w1.y:(i==2)?w1.z:w1.w;
      float c2 = (i==0)?w2.x:(i==1)?w2.y:(i==2)?w2.z:w2.w;
      float c3 = (i==0)?w3.x:(i==1)?w3.y:(i==2)?w3.z:w3.w;
      a0 += c0*x0; a1 += c1*x1; a2 += c2*x2; a3 += c3*x3;
    }
  }
  float y0 = a0 * sigmoidf_(a0);
  float y1 = a1 * sigmoidf_(a1);
  float y2 = a2 * sigmoidf_(a2);
  float y3 = a3 * sigmoidf_(a3);
  short4v o;
  o.x=(short)f2bfbits(y0); o.y=(short)f2bfbits(y1);
  o.z=(short)f2bfbits(y2); o.w=(short)f2bfbits(y3);
  *(short4v*)(xcH + idx) = o;
}

// ---------------------------------------------------------------------------
// Chunked selective scan (lane layout validated R7, GSTEP=8 validated R11).
// R23: R22's LDS staging REVERTED (emit 40->49us: old per-lane loads were
// already 32B-coalesced+broadcast-merged and 8-deep prefetched; staging
// added overhead on a latency-bound kernel). NCHUNK 32->64 (CLEN=16):
// 4096 blocks = 16 blocks/CU doubles TLP on the validated lever (16->32
// helped the same way). delta bf16 (validated R18).
// ---------------------------------------------------------------------------
#define GSTEP 8

__global__ __launch_bounds__(256)
void stats_k(const __hip_bfloat16* __restrict__ delta,
             const __hip_bfloat16* __restrict__ xcH,
             const float* __restrict__ xdbl,
             const float* __restrict__ alF,
             float* __restrict__ Hc, float* __restrict__ Sd)
{
  __shared__ alignas(16) float Bs[CLEN*16];     // 1 KB
  const int bid  = blockIdx.x;                  // b*2048 + c*32 + cg
  const int b    = bid >> 11;
  const int c    = (bid >> 5) & (NCHUNK-1);
  const int cg   = bid & 31;
  const int tid  = threadIdx.x;
  const int lane = tid & 63;
  const int wave = tid >> 6;
  const int sub  = lane & 3;
  const int ch   = (cg << 6) + (wave << 4) + (lane >> 2);

  const size_t rb = (size_t)b * SEQ + (size_t)c * CLEN;

  for (int i = tid; i < CLEN*16; i += 256) {
    int t = i >> 4, j = i & 15;
    Bs[i] = xdbl[(rb + t)*96 + 64 + j];
  }
  __syncthreads();

  float negA[4];
#pragma unroll
  for (int j = 0; j < 4; ++j) negA[j] = -__expf(alF[ch*NSTATE + sub*4 + j]);

  const __hip_bfloat16* dp = delta + rb * DINNER + ch;
  const __hip_bfloat16* xp = xcH   + rb * DINNER + ch;

  float h0=0.f,h1=0.f,h2=0.f,h3=0.f, sd=0.f;
  float d0[GSTEP], x0[GSTEP], d1[GSTEP], x1[GSTEP];

#define PF1(D_,X_,T0) \
  _Pragma("unroll") \
  for (int u = 0; u < GSTEP; ++u) { \
    D_[u] = bf2f(dp[(size_t)((T0)+u) * DINNER]); \
    X_[u] = bf2f(xp[(size_t)((T0)+u) * DINNER]); \
  }
#define ST1(D_,X_,T0) \
  _Pragma("unroll") \
  for (int u = 0; u < GSTEP; ++u) { \
    float d_ = D_[u]; \
    sd += d_; \
    float du = d_ * X_[u]; \
    f32x4 B4 = *(const f32x4*)&Bs[((T0)+u)*16 + sub*4]; \
    h0 = __expf(d_*negA[0])*h0 + du*B4.x; \
    h1 = __expf(d_*negA[1])*h1 + du*B4.y; \
    h2 = __expf(d_*negA[2])*h2 + du*B4.z; \
    h3 = __expf(d_*negA[3])*h3 + du*B4.w; \
  }

  PF1(d0, x0, 0)
  for (int t0 = 0; t0 < CLEN; t0 += 2*GSTEP) {
    PF1(d1, x1, t0 + GSTEP)
    ST1(d0, x0, t0)
    if (t0 + 2*GSTEP < CLEN) { PF1(d0, x0, t0 + 2*GSTEP) }
    ST1(d1, x1, t0 + GSTEP)
  }
#undef PF1
#undef ST1

  const size_t bc = (size_t)(b*NCHUNK + c);
  f32x4 hv = { h0, h1, h2, h3 };
  *(f32x4*)&Hc[(bc*DINNER + ch)*NSTATE + sub*4] = hv;
  if (sub == 0) Sd[bc*DINNER + ch] = sd;
}

__global__ __launch_bounds__(256)
void carry_k(const float* __restrict__ Hc, const float* __restrict__ Sd,
             const float* __restrict__ alF, float* __restrict__ hin)
{
  int i = blockIdx.x * 256 + threadIdx.x;       // BATCH*DINNER*NSTATE = 65536
  int n  = i & (NSTATE-1);
  int ch = (i >> 4) & (DINNER-1);
  int b  = i >> 15;
  float negA = -__expf(alF[ch * NSTATE + n]);
  float h = 0.f;
#pragma unroll
  for (int c = 0; c < NCHUNK; ++c) {
    size_t bc = (size_t)(b*NCHUNK + c);
    hin[(bc*DINNER + ch)*NSTATE + n] = h;
    float P = __expf(negA * Sd[bc*DINNER + ch]);
    h = P * h + Hc[(bc*DINNER + ch)*NSTATE + n];
  }
}

__global__ __launch_bounds__(256)
void emit_k(const __hip_bfloat16* __restrict__ delta,
            const __hip_bfloat16* __restrict__ xcH,
            const float* __restrict__ xdbl,
            const __hip_bfloat16* __restrict__ zsH,
            const float* __restrict__ alF,
            const float* __restrict__ DF,
            const float* __restrict__ hin,
            __hip_bfloat16* __restrict__ yH)
{
  __shared__ alignas(16) float BCs[CLEN*32];          // 2 KB
  __shared__ alignas(16) unsigned short yS[CLEN*72];  // 2.25 KB (72 = 64+8 pad)
  const int bid  = blockIdx.x;
  const int b    = bid >> 11;
  const int c    = (bid >> 5) & (NCHUNK-1);
  const int cg   = bid & 31;
  const int tid  = threadIdx.x;
  const int lane = tid & 63;
  const int wave = tid >> 6;
  const int sub  = lane & 3;
  const int chL  = (wave << 4) + (lane >> 2);   // 0..63 within block
  const int ch   = (cg << 6) + chL;

  const size_t rb = (size_t)b * SEQ + (size_t)c * CLEN;

  for (int i = tid; i < CLEN*32; i += 256) {
    int t = i >> 5, j = i & 31;
    BCs[i] = xdbl[(rb + t)*96 + 64 + j];
  }
  __syncthreads();

  float negA[4];
#pragma unroll
  for (int j = 0; j < 4; ++j) negA[j] = -__expf(alF[ch*NSTATE + sub*4 + j]);
  const float Dch = DF[ch];

  const __hip_bfloat16* dp = delta + rb * DINNER + ch;
  const __hip_bfloat16* xp = xcH   + rb * DINNER + ch;
  const __hip_bfloat16* zp = zsH   + rb * DINNER + ch;

  f32x4 hv = *(const f32x4*)&hin[((size_t)(b*NCHUNK + c)*DINNER + ch)*NSTATE + sub*4];
  float h0=hv.x, h1=hv.y, h2=hv.z, h3=hv.w;

  float d0[GSTEP], x0[GSTEP], z0[GSTEP], d1[GSTEP], x1[GSTEP], z1[GSTEP];

#define PF(D_,X_,Z_,T0) \
  _Pragma("unroll") \
  for (int u = 0; u < GSTEP; ++u) { \
    D_[u] = bf2f(dp[(size_t)((T0)+u) * DINNER]); \
    X_[u] = bf2f(xp[(size_t)((T0)+u) * DINNER]); \
    Z_[u] = bf2f(zp[(size_t)((T0)+u) * DINNER]); \
  }
#define STEPS(D_,X_,Z_,T0) \
  _Pragma("unroll") \
  for (int u = 0; u < GSTEP; ++u) { \
    float d_ = D_[u]; \
    float du = d_ * X_[u]; \
    f32x4 B4 = *(const f32x4*)&BCs[((T0)+u)*32 + sub*4]; \
    f32x4 C4 = *(const f32x4*)&BCs[((T0)+u)*32 + 16 + sub*4]; \
    h0 = __expf(d_*negA[0])*h0 + du*B4.x; \
    h1 = __expf(d_*negA[1])*h1 + du*B4.y; \
    h2 = __expf(d_*negA[2])*h2 + du*B4.z; \
    h3 = __expf(d_*negA[3])*h3 + du*B4.w; \
    float p = h0*C4.x + h1*C4.y + h2*C4.z + h3*C4.w; \
    p += __shfl_xor(p, 1); \
    p += __shfl_xor(p, 2); \
    if (sub == 0) { \
      float y = (p + X_[u] * Dch) * Z_[u]; \
      yS[((T0)+u)*72 + chL] = f2bfbits(y); \
    } \
  }

  PF(d0, x0, z0, 0)
  for (int t0 = 0; t0 < CLEN; t0 += 2*GSTEP) {
    PF(d1, x1, z1, t0 + GSTEP)
    STEPS(d0, x0, z0, t0)
    if (t0 + 2*GSTEP < CLEN) { PF(d0, x0, z0, t0 + 2*GSTEP) }
    STEPS(d1, x1, z1, t0 + GSTEP)
  }
#undef PF
#undef STEPS

  // coalesced y flush: 128 threads x 16B = 2 KB slab (16 t x 64 ch)
  __syncthreads();
  if (tid < 128) {
    int t2 = tid >> 3, p2 = tid & 7;
    short8 v = *(const short8*)&yS[t2*72 + p2*8];
    *(short8*)(yH + (rb + t2)*DINNER + (cg << 6) + p2*8) = v;
  }
}

// ---------------------------------------------------------------------------
extern "C" void kernel_launch(void* const* d_in, const int* in_sizes, int n_in,
                              void* d_out, int out_size, void* d_ws, size_t ws_size,
                              hipStream_t stream)
{
  float* out = (float*)d_out;   // reference output dtype: float32
  char* ws = (char*)d_ws;
  const size_t MB = 1024*1024;

  // workspace layout (101 MB, liveness-aliased; ws_size = 256 MB)
  // scalar region offsets: VALIDATED R13 layout — do not renumber.
  int*            flag    = (int*)            (ws);
  float*          cwF     = (float*)          (ws + 1024);
  float*          cbF     = (float*)          (ws + 40*1024);
  float*          dtbF    = (float*)          (ws + 56*1024);
  float*          alF     = (float*)          (ws + 72*1024);
  float*          DF      = (float*)          (ws + 208*1024);
  __hip_bfloat16* xB      = (__hip_bfloat16*) (ws + 1*MB);          // 4 MB  (dead after G1)
  __hip_bfloat16* inpB    = (__hip_bfloat16*) (ws + 5*MB);          // 8 MB
  __hip_bfloat16* xiB     = (__hip_bfloat16*) (ws + 13*MB);         // 8 MB  (dead after conv)
  __hip_bfloat16* dltH    = (__hip_bfloat16*) (ws + 1*MB);          // 8 MB bf16 delta, aliases xB/inpB[:4MB]
  __hip_bfloat16* xprojB  = (__hip_bfloat16*) (ws + 21*MB);
  __hip_bfloat16* dtprojB = (__hip_bfloat16*) (ws + 21*MB + 512*1024);
  __hip_bfloat16* outpB   = (__hip_bfloat16*) (ws + 22*MB);         // 4 MB
  __hip_bfloat16* zsH     = (__hip_bfloat16*) (ws + 26*MB);         // 8 MB (bf16 silu(z))
  __hip_bfloat16* xcH     = (__hip_bfloat16*) (ws + 42*MB);         // 8 MB
  float*          xdbl    = (float*)          (ws + 50*MB);         // 768 KB
  __hip_bfloat16* yH      = (__hip_bfloat16*) (ws + 52*MB);         // 8 MB (live into out_proj)
  float*          Hc      = (float*)          (ws + 68*MB);         // 16 MB (NCHUNK=64)
  float*          hin     = (float*)          (ws + 84*MB);         // 16 MB -> 100 MB
  float*          Sd      = (float*)          (ws + 100*MB);        // 1 MB (NCHUNK=64) -> 101 MB
  // out_proj f32 partials (8 MB each), regions dead after emit_k:
  float*          q0      = (float*)          (ws + 1*MB);          // dltH (dead)
  float*          q1      = (float*)          (ws + 9*MB);          // xiB lo (dead)
  float*          q2      = (float*)          (ws + 26*MB);         // zsH (dead)
  float*          q3      = (float*)          (ws + 34*MB);         // free

  dim3 blk(256);

  // 0) sniff (1 tiny block) + vectorized canonicalize (+ xdbl zero-init)
  sniff_k<<<1, 64, 0, stream>>>((const unsigned short*)d_in[0], flag);
  CvtArgs ca = { d_in[0], d_in[1], d_in[2], d_in[3], d_in[4],
                 d_in[5], d_in[6], d_in[7], d_in[8], d_in[9],
                 xB, inpB, xprojB, dtprojB, outpB,
                 cwF, cbF, dtbF, alF, DF, xdbl, flag };
  convert_all_k<<<CVT_BLOCKS, blk, 0, stream>>>(ca);

  // 1) in_proj (2048 x 4096 x 1024): BK=128, XCD-swizzled, split -> xi, silu(z)
  gemm64<4,2,1><<<dim3(4096/128, ROWS/128), blk, 0, stream>>>(
      xB, inpB, ROWS, 2*DINNER, DMODEL, 0, nullptr, xiB, zsH, nullptr,
      nullptr, nullptr, nullptr, nullptr);

  // 2) xc = silu(depthwise_conv(xi) + b), x4 vectorized
  conv_silu_k<<<(ROWS*DINNER/4)/256, blk, 0, stream>>>(xiB, cwF, cbF, xcH);

  // 3) x_dbl (2048 x 96 x 2048): 16-way split-K (kchunk=128), atomic into xdbl
  gemm64<5,2,0><<<dim3(1, ROWS/128, KSPLIT), blk, 0, stream>>>(
      xcH, xprojB, ROWS, 96, DINNER, DINNER/KSPLIT, xdbl, nullptr, nullptr, nullptr,
      nullptr, nullptr, nullptr, nullptr);

  // 4) delta = softplus(dt @ dt_proj^T + dt_b) (2048 x 2048 x 64):
  //    A staged directly from f32 xdbl (fused dt conversion), output bf16.
  gemm64<3,1,0><<<dim3(DINNER/128, ROWS/128), blk, 0, stream>>>(
      (const __hip_bfloat16*)xdbl, dtprojB, ROWS, DINNER, DTRANK, 0,
      nullptr, dltH, nullptr, dtbF,
      nullptr, nullptr, nullptr, nullptr);

  // 5) chunked selective scan (NCHUNK=64) + fused combine -> bf16 yH
  stats_k<<<BATCH*NCHUNK*32, blk, 0, stream>>>(dltH, xcH, xdbl, alF, Hc, Sd);
  carry_k<<<(BATCH*DINNER*NSTATE)/256, blk, 0, stream>>>(Hc, Sd, alF, hin);
  emit_k<<<BATCH*NCHUNK*32, blk, 0, stream>>>(dltH, xcH, xdbl, zsH, alF, DF, hin, yH);

  // 6) out_proj (2048 x 1024 x 2048): BK=128, XCD-swizzled, split-K=4 + reduce
  gemm64<6,2,1><<<dim3(DMODEL/128, ROWS/128, 4), blk, 0, stream>>>(
      yH, outpB, ROWS, DMODEL, DINNER, DINNER/4, nullptr, nullptr, nullptr, nullptr,
      q0, q1, q2, q3);
  reduce_out_k<<<(ROWS*DMODEL/4)/256, blk, 0, stream>>>(q0, q1, q2, q3, out);
}

// Round 10
// 225.506 us; speedup vs baseline: 1.0755x; 1.0142x over previous
//
#include <hip/hip_runtime.h>
#include <hip/hip_bf16.h>
#include <cstdint>
#include <cstddef>

#define DMODEL 1024
#define DINNER 2048
#define NSTATE 16
#define DTRANK 64
#define BATCH 2
#define SEQ 1024
#define ROWS (BATCH*SEQ)   // 2048 token rows
#define NCHUNK 32
#define CLEN (SEQ/NCHUNK)  // 32
#define KSPLIT 16          // split-K ways for x_proj GEMM

typedef __attribute__((ext_vector_type(8))) short short8;
typedef __attribute__((ext_vector_type(4))) short short4v;
typedef __attribute__((ext_vector_type(4))) float f32x4;
typedef __attribute__((ext_vector_type(16))) float f32x16;

__device__ __forceinline__ float bf2f(__hip_bfloat16 h){ return __bfloat162float(h); }
__device__ __forceinline__ float sigmoidf_(float x){ return 1.0f/(1.0f + __expf(-x)); }
__device__ __forceinline__ unsigned short f2bfbits(float v){
  __hip_bfloat16 h = __float2bfloat16(v);
  return *(unsigned short*)&h;
}
__device__ __forceinline__ float bfbits2f(unsigned short u){
  unsigned int x = ((unsigned int)u) << 16;
  return *(float*)&x;
}

__device__ __forceinline__ void gld16(const void* g, void* l){
  __builtin_amdgcn_global_load_lds((const __attribute__((address_space(1))) void*)g,
                                   (__attribute__((address_space(3))) void*)l, 16, 0, 0);
}

// ---------------------------------------------------------------------------
// dtype sniffer — separate tiny kernel (R8 lesson).
// ---------------------------------------------------------------------------
__global__ void sniff_k(const unsigned short* __restrict__ xu, int* __restrict__ flag)
{
  int t = threadIdx.x;           // 64 threads
  int cnt = 0;
  for (int i = t; i < 1024; i += 64) {
    unsigned short u = xu[i];
    int e = (u >> 7) & 0xFF;
    if (e >= 0x70 && e <= 0x86) cnt++;
  }
  for (int o = 32; o; o >>= 1) cnt += __shfl_down(cnt, o);
  if (t == 0) *flag = (cnt >= 768) ? 0 : 1;
}

// ---------------------------------------------------------------------------
// Fused canonicalizer, x4 vectorized (validated R10/R11) + zero-init of xdbl.
// ---------------------------------------------------------------------------
struct CvtArgs {
  const void *s0,*s1,*s2,*s3,*s4,*s5,*s6,*s7,*s8,*s9;
  __hip_bfloat16 *xB,*inpB,*xprojB,*dtprojB,*outpB;
  float *cwF,*cbF,*dtbF,*alF,*DF;
  float *xdblZ;
  const int* flag;
};
#define CVT_C1 2097152
#define CVT_C2 6291456
#define CVT_C3 6299648
#define CVT_C4 6301696
#define CVT_C5 6498304
#define CVT_C6 6629376
#define CVT_C7 6631424
#define CVT_C8 6664192
#define CVT_C9 6666240
#define CVT_TOT 8763392
#define CVT_BLOCKS (CVT_TOT/4/256)   // 8558

__device__ __forceinline__ void cvt_read4(const void* s, int j, int fl, float v[4]){
  if (fl) {
    f32x4 t = ((const f32x4*)s)[j>>2];
    v[0]=t.x; v[1]=t.y; v[2]=t.z; v[3]=t.w;
  } else {
    short4v t = *(const short4v*)((const __hip_bfloat16*)s + j);
    v[0]=bfbits2f((unsigned short)t.x); v[1]=bfbits2f((unsigned short)t.y);
    v[2]=bfbits2f((unsigned short)t.z); v[3]=bfbits2f((unsigned short)t.w);
  }
}
__device__ __forceinline__ void cvt_wB(__hip_bfloat16* d, int j, const float v[4]){
  short4v o;
  o.x=(short)f2bfbits(v[0]); o.y=(short)f2bfbits(v[1]);
  o.z=(short)f2bfbits(v[2]); o.w=(short)f2bfbits(v[3]);
  *(short4v*)(d + j) = o;
}
__device__ __forceinline__ void cvt_wF(float* d, int j, const float v[4]){
  f32x4 o = { v[0], v[1], v[2], v[3] };
  *(f32x4*)(d + j) = o;
}

__global__ __launch_bounds__(256)
void convert_all_k(CvtArgs a)
{
  int i4 = blockIdx.x * 256 + threadIdx.x;
  const int fl = *a.flag;

  if (blockIdx.x < 192) {                       // xdbl: 49152 f32x4 exactly
    f32x4 z = {0.f, 0.f, 0.f, 0.f};
    ((f32x4*)a.xdblZ)[i4] = z;
  }

  int i = i4 * 4;
  if (i >= CVT_TOT) return;
  float v[4];
  if (i < CVT_C1)      { cvt_read4(a.s0, i, fl, v);        cvt_wB(a.xB, i, v); }
  else if (i < CVT_C2) { cvt_read4(a.s1, i-CVT_C1, fl, v); cvt_wB(a.inpB, i-CVT_C1, v); }
  else if (i < CVT_C3) { cvt_read4(a.s2, i-CVT_C2, fl, v); cvt_wF(a.cwF, i-CVT_C2, v); }
  else if (i < CVT_C4) { cvt_read4(a.s3, i-CVT_C3, fl, v); cvt_wF(a.cbF, i-CVT_C3, v); }
  else if (i < CVT_C5) { cvt_read4(a.s4, i-CVT_C4, fl, v); cvt_wB(a.xprojB, i-CVT_C4, v); }
  else if (i < CVT_C6) { cvt_read4(a.s5, i-CVT_C5, fl, v); cvt_wB(a.dtprojB, i-CVT_C5, v); }
  else if (i < CVT_C7) { cvt_read4(a.s6, i-CVT_C6, fl, v); cvt_wF(a.dtbF, i-CVT_C6, v); }
  else if (i < CVT_C8) { cvt_read4(a.s7, i-CVT_C7, fl, v); cvt_wF(a.alF, i-CVT_C7, v); }
  else if (i < CVT_C9) { cvt_read4(a.s8, i-CVT_C8, fl, v); cvt_wF(a.DF, i-CVT_C8, v); }
  else                 { cvt_read4(a.s9, i-CVT_C9, fl, v); cvt_wB(a.outpB, i-CVT_C9, v); }
}

// ---------------------------------------------------------------------------
// NT GEMM: XOR-swizzled LDS staging (validated R8/R9), mfma_f32_32x32x16_bf16
// (validated R17), NBUF template BK=64*NBUF (validated neutral R19),
// SWZ XCD remap (validated R21, -1.5us).
// R24: 512-thread blocks, 8 waves in a 2(row)x4(col) grid over the SAME
// 128x128 tile — R8 counters showed Occ 19% / MfmaUtil 12.6% / HBM 13%
// (latency-bound at 2 blocks/CU, grid-capped). Doubling waves/CU (8->16)
// with identical tiles/fetch/barriers/math-order is the pure-TLP lever.
// Each wave: 64x32 output, acc[2] (2x 32x32 frags), 8 MFMA/K-iter.
// C/D layout col=lane&31, row=(reg&3)+8*(reg>>2)+4*(lane>>5) [m74/m101].
// R16 lesson: NO device-scope fences in the epilogue (107us stall).
// EPI: 3 = dt_proj: A staged from f32 xdbl (stride 96, k<64), softplus->bf16
//      4 = in_proj split: col<2048 -> bf16 xi; col>=2048 -> silu -> bf16
//      5 = split-K atomic into f32 xdbl [row,96] (x_proj)
//      6 = split-K f32 partial -> q[z] (plain stores; reduce_out_k sums)
// ---------------------------------------------------------------------------
template<int EPI, int NBUF, int SWZ>
__global__ __launch_bounds__(512)
void gemm64(const __hip_bfloat16* __restrict__ A,
            const __hip_bfloat16* __restrict__ W,
            int M, int N, int K, int kchunk,
            float* __restrict__ outF,
            __hip_bfloat16* __restrict__ outH,
            __hip_bfloat16* __restrict__ outH2,
            const float* __restrict__ biasF,
            float* __restrict__ q0, float* __restrict__ q1,
            float* __restrict__ q2, float* __restrict__ q3)
{
  __shared__ alignas(16) __hip_bfloat16 As[NBUF][128*64];   // 16 KB each
  __shared__ alignas(16) __hip_bfloat16 Ws[NBUF][128*64];
  const int tid  = threadIdx.x;
  const int lane = tid & 63;
  const int wave = tid >> 6;          // 0..7
  const int wm = wave & 1;            // 2 row-groups of 64
  const int wn = wave >> 1;           // 4 col-groups of 32

  int bx = blockIdx.x, by = blockIdx.y, bz = blockIdx.z;
  if (SWZ) {
    const int nx = gridDim.x, ny = gridDim.y;
    const int id  = (blockIdx.z * ny + blockIdx.y) * nx + blockIdx.x;
    const int nwg = nx * ny * gridDim.z;
    const int rid = (id & 7) * (nwg >> 3) + (id >> 3);
    bx = rid % nx;
    const int t2 = rid / nx;
    by = t2 % ny;
    bz = t2 / ny;
  }
  const int row0 = by * 128;
  const int col0 = bx * 128;

  f32x16 acc[2] = {};

  int kbeg = 0, kend = K;
  if (EPI == 5 || EPI == 6) { kbeg = bz * kchunk; kend = kbeg + kchunk; }

  const int r32   = lane & 31;
  const int khalf = lane >> 5;
  const int swz   = r32 & 7;

  for (int k0 = kbeg; k0 < kend; k0 += 64*NBUF) {
#pragma unroll
    for (int h = 0; h < NBUF; ++h) {
      if (EPI == 3) {
        const float* Af32 = (const float*)A;
#pragma unroll
        for (int j = 0; j < 2; ++j) {
          int e = tid + j*512;
          int r = e >> 3, g = e & 7;
          int kc = ((g ^ (r & 7)) << 3);
          const float* src = Af32 + (size_t)(row0 + r) * 96 + kc;
          f32x4 v0 = *(const f32x4*)(src);
          f32x4 v1 = *(const f32x4*)(src + 4);
          short8 o;
          o[0]=(short)f2bfbits(v0.x); o[1]=(short)f2bfbits(v0.y);
          o[2]=(short)f2bfbits(v0.z); o[3]=(short)f2bfbits(v0.w);
          o[4]=(short)f2bfbits(v1.x); o[5]=(short)f2bfbits(v1.y);
          o[6]=(short)f2bfbits(v1.z); o[7]=(short)f2bfbits(v1.w);
          *(short8*)((char*)As[h] + (size_t)e*16) = o;
        }
      } else {
#pragma unroll
        for (int j = 0; j < 2; ++j) {             // A tile, half h
          int e = tid + j*512;
          int r = e >> 3, g = e & 7;
          int kc = ((g ^ (r & 7)) << 3);
          gld16(A + (size_t)(row0 + r) * K + k0 + h*64 + kc, (char*)As[h] + (size_t)e*16);
        }
      }
#pragma unroll
      for (int j = 0; j < 2; ++j) {             // W tile, half h
        int e = tid + j*512;
        int r = e >> 3, g = e & 7;
        int kc = ((g ^ (r & 7)) << 3);
        int rw = col0 + r; if (EPI == 5 && rw > N-1) rw = N-1;
        gld16(W + (size_t)rw * K + k0 + h*64 + kc, (char*)Ws[h] + (size_t)e*16);
      }
    }
    __syncthreads();

#pragma unroll
    for (int h = 0; h < NBUF; ++h) {
      const char* Ab = (const char*)As[h] + ((wm*64 + r32) * 128);
      const char* Wb = (const char*)Ws[h] + ((wn*32 + r32) * 128);
#pragma unroll
      for (int ks = 0; ks < 4; ++ks) {
        const int sx = (((ks*2 + khalf) ^ swz) * 16);
        short8 a0 = *(const short8*)(Ab + sx);
        short8 a1 = *(const short8*)(Ab + 32*128 + sx);
        short8 w0 = *(const short8*)(Wb + sx);
        acc[0] = __builtin_amdgcn_mfma_f32_32x32x16_bf16(a0, w0, acc[0], 0, 0, 0);
        acc[1] = __builtin_amdgcn_mfma_f32_32x32x16_bf16(a1, w0, acc[1], 0, 0, 0);
      }
    }
    __syncthreads();
  }

  // C/D layout (m74/m101): col = lane&31, row = (reg&3) + 8*(reg>>2) + 4*(lane>>5)
  const int mbase = row0 + wm*64 + 4*khalf;
  const int nbase = col0 + wn*32 + r32;

  float bv0 = 0.f;
  if (EPI == 3) bv0 = biasF[nbase];
  float* qz = nullptr;
  if (EPI == 6) qz = (bz == 0) ? q0 : (bz == 1) ? q1
                   : (bz == 2) ? q2 : q3;

#pragma unroll
  for (int mt = 0; mt < 2; ++mt) {
#pragma unroll
    for (int r = 0; r < 16; ++r) {
      int row = mbase + mt*32 + (r & 3) + 8*(r >> 2);
      int col = nbase;
      float v = acc[mt][r];
      if (EPI == 3) {
        v += bv0;
        float sp = fmaxf(v, 0.0f) + __logf(1.0f + __expf(-fabsf(v)));
        outH[(size_t)row * DINNER + col] = __float2bfloat16(sp);
      } else if (EPI == 4) {
        if (col < DINNER) {
          outH[(size_t)row * DINNER + col] = __float2bfloat16(v);
        } else {
          outH2[(size_t)row * DINNER + (col - DINNER)] = __float2bfloat16(v * sigmoidf_(v));
        }
      } else if (EPI == 5) {
        if (col < 96)
          unsafeAtomicAdd(&outF[(size_t)row * 96 + col], v);
      } else if (EPI == 6) {
        qz[(size_t)row * DMODEL + col] = v;
      }
    }
  }
}

// ---------------------------------------------------------------------------
// out_proj split-K reduce: out = q0+q1+q2+q3, f32x4 vectorized
// ---------------------------------------------------------------------------
__global__ __launch_bounds__(256)
void reduce_out_k(const float* __restrict__ q0, const float* __restrict__ q1,
                  const float* __restrict__ q2, const float* __restrict__ q3,
                  float* __restrict__ out)
{
  int i4 = blockIdx.x * 256 + threadIdx.x;     // ROWS*DMODEL/4 = 524288
  if (i4 >= ROWS*DMODEL/4) return;
  f32x4 a = ((const f32x4*)q0)[i4];
  f32x4 b = ((const f32x4*)q1)[i4];
  f32x4 c = ((const f32x4*)q2)[i4];
  f32x4 d = ((const f32x4*)q3)[i4];
  f32x4 o = { (a.x+b.x)+(c.x+d.x), (a.y+b.y)+(c.y+d.y),
              (a.z+b.z)+(c.z+d.z), (a.w+b.w)+(c.w+d.w) };
  ((f32x4*)out)[i4] = o;
}

// ---------------------------------------------------------------------------
// Depthwise causal conv + bias + SiLU, x4 vectorized (validated R12).
// ---------------------------------------------------------------------------
__global__ __launch_bounds__(256)
void conv_silu_k(const __hip_bfloat16* __restrict__ xi,
                 const float* __restrict__ cw,
                 const float* __restrict__ cb,
                 __hip_bfloat16* __restrict__ xcH)
{
  int idx4 = blockIdx.x * 256 + threadIdx.x;   // ROWS*DINNER/4 threads
  int idx  = idx4 * 4;
  int d  = idx & (DINNER - 1);
  int t  = (idx >> 11) & (SEQ - 1);
  int bt = idx >> 11;

  f32x4 cb4 = *(const f32x4*)&cb[d];
  float a0=cb4.x, a1=cb4.y, a2=cb4.z, a3=cb4.w;
  f32x4 w0 = *(const f32x4*)&cw[(d+0)*4];
  f32x4 w1 = *(const f32x4*)&cw[(d+1)*4];
  f32x4 w2 = *(const f32x4*)&cw[(d+2)*4];
  f32x4 w3 = *(const f32x4*)&cw[(d+3)*4];

#pragma unroll
  for (int i = 0; i < 4; ++i) {
    if (t - 3 + i >= 0) {
      short4v xv = *(const short4v*)(xi + (size_t)(bt - 3 + i) * DINNER + d);
      float x0 = bfbits2f((unsigned short)xv.x);
      float x1 = bfbits2f((unsigned short)xv.y);
      float x2 = bfbits2f((unsigned short)xv.z);
      float x3 = bfbits2f((unsigned short)xv.w);
      float c0 = (i==0)?w0.x:(i==1)?w0.y:(i==2)?w0.z:w0.w;
      float c1 = (i==0)?w1.x:(i==1)?w1.y:(i==2)?w1.z:w1.w;
      float c2 = (i==0)?w2.x:(i==1)?w2.y:(i==2)?w2.z:w2.w;
      float c3 = (i==0)?w3.x:(i==1)?w3.y:(i==2)?w3.z:w3.w;
      a0 += c0*x0; a1 += c1*x1; a2 += c2*x2; a3 += c3*x3;
    }
  }
  float y0 = a0 * sigmoidf_(a0);
  float y1 = a1 * sigmoidf_(a1);
  float y2 = a2 * sigmoidf_(a2);
  float y3 = a3 * sigmoidf_(a3);
  short4v o;
  o.x=(short)f2bfbits(y0); o.y=(short)f2bfbits(y1);
  o.z=(short)f2bfbits(y2); o.w=(short)f2bfbits(y3);
  *(short4v*)(xcH + idx) = o;
}

// ---------------------------------------------------------------------------
// Chunked selective scan — exact R21 form (validated 226.5us): NCHUNK=32,
// per-lane scalar loads (32B-coalesced + broadcast-merged, 8-deep prefetch).
// R22's LDS staging regressed (emit 40->49us) and R23's NCHUNK=64 was
// neutral-negative — both reverted. delta bf16 (validated R18).
// ---------------------------------------------------------------------------
#define GSTEP 8

__global__ __launch_bounds__(256)
void stats_k(const __hip_bfloat16* __restrict__ delta,
             const __hip_bfloat16* __restrict__ xcH,
             const float* __restrict__ xdbl,
             const float* __restrict__ alF,
             float* __restrict__ Hc, float* __restrict__ Sd)
{
  __shared__ alignas(16) float Bs[CLEN*16];     // 2 KB
  const int bid  = blockIdx.x;                  // b*1024 + c*32 + cg
  const int b    = bid >> 10;
  const int c    = (bid >> 5) & (NCHUNK-1);
  const int cg   = bid & 31;
  const int tid  = threadIdx.x;
  const int lane = tid & 63;
  const int wave = tid >> 6;
  const int sub  = lane & 3;
  const int ch   = (cg << 6) + (wave << 4) + (lane >> 2);

  const size_t rb = (size_t)b * SEQ + (size_t)c * CLEN;

  for (int i = tid; i < CLEN*16; i += 256) {
    int t = i >> 4, j = i & 15;
    Bs[i] = xdbl[(rb + t)*96 + 64 + j];
  }
  __syncthreads();

  float negA[4];
#pragma unroll
  for (int j = 0; j < 4; ++j) negA[j] = -__expf(alF[ch*NSTATE + sub*4 + j]);

  const __hip_bfloat16* dp = delta + rb * DINNER + ch;
  const __hip_bfloat16* xp = xcH   + rb * DINNER + ch;

  float h0=0.f,h1=0.f,h2=0.f,h3=0.f, sd=0.f;
  float d0[GSTEP], x0[GSTEP], d1[GSTEP], x1[GSTEP];

#define PF1(D_,X_,T0) \
  _Pragma("unroll") \
  for (int u = 0; u < GSTEP; ++u) { \
    D_[u] = bf2f(dp[(size_t)((T0)+u) * DINNER]); \
    X_[u] = bf2f(xp[(size_t)((T0)+u) * DINNER]); \
  }
#define ST1(D_,X_,T0) \
  _Pragma("unroll") \
  for (int u = 0; u < GSTEP; ++u) { \
    float d_ = D_[u]; \
    sd += d_; \
    float du = d_ * X_[u]; \
    f32x4 B4 = *(const f32x4*)&Bs[((T0)+u)*16 + sub*4]; \
    h0 = __expf(d_*negA[0])*h0 + du*B4.x; \
    h1 = __expf(d_*negA[1])*h1 + du*B4.y; \
    h2 = __expf(d_*negA[2])*h2 + du*B4.z; \
    h3 = __expf(d_*negA[3])*h3 + du*B4.w; \
  }

  PF1(d0, x0, 0)
  for (int t0 = 0; t0 < CLEN; t0 += 2*GSTEP) {
    PF1(d1, x1, t0 + GSTEP)
    ST1(d0, x0, t0)
    if (t0 + 2*GSTEP < CLEN) { PF1(d0, x0, t0 + 2*GSTEP) }
    ST1(d1, x1, t0 + GSTEP)
  }
#undef PF1
#undef ST1

  const size_t bc = (size_t)(b*NCHUNK + c);
  f32x4 hv = { h0, h1, h2, h3 };
  *(f32x4*)&Hc[(bc*DINNER + ch)*NSTATE + sub*4] = hv;
  if (sub == 0) Sd[bc*DINNER + ch] = sd;
}

__global__ __launch_bounds__(256)
void carry_k(const float* __restrict__ Hc, const float* __restrict__ Sd,
             const float* __restrict__ alF, float* __restrict__ hin)
{
  int i = blockIdx.x * 256 + threadIdx.x;       // BATCH*DINNER*NSTATE = 65536
  int n  = i & (NSTATE-1);
  int ch = (i >> 4) & (DINNER-1);
  int b  = i >> 15;
  float negA = -__expf(alF[ch * NSTATE + n]);
  float h = 0.f;
#pragma unroll
  for (int c = 0; c < NCHUNK; ++c) {
    size_t bc = (size_t)(b*NCHUNK + c);
    hin[(bc*DINNER + ch)*NSTATE + n] = h;
    float P = __expf(negA * Sd[bc*DINNER + ch]);
    h = P * h + Hc[(bc*DINNER + ch)*NSTATE + n];
  }
}

__global__ __launch_bounds__(256)
void emit_k(const __hip_bfloat16* __restrict__ delta,
            const __hip_bfloat16* __restrict__ xcH,
            const float* __restrict__ xdbl,
            const __hip_bfloat16* __restrict__ zsH,
            const float* __restrict__ alF,
            const float* __restrict__ DF,
            const float* __restrict__ hin,
            __hip_bfloat16* __restrict__ yH)
{
  __shared__ alignas(16) float BCs[CLEN*32];          // 4 KB
  __shared__ alignas(16) unsigned short yS[CLEN*72];  // 4.5 KB (72 = 64+8 pad)
  const int bid  = blockIdx.x;
  const int b    = bid >> 10;
  const int c    = (bid >> 5) & (NCHUNK-1);
  const int cg   = bid & 31;
  const int tid  = threadIdx.x;
  const int lane = tid & 63;
  const int wave = tid >> 6;
  const int sub  = lane & 3;
  const int chL  = (wave << 4) + (lane >> 2);   // 0..63 within block
  const int ch   = (cg << 6) + chL;

  const size_t rb = (size_t)b * SEQ + (size_t)c * CLEN;

  for (int i = tid; i < CLEN*32; i += 256) {
    int t = i >> 5, j = i & 31;
    BCs[i] = xdbl[(rb + t)*96 + 64 + j];
  }
  __syncthreads();

  float negA[4];
#pragma unroll
  for (int j = 0; j < 4; ++j) negA[j] = -__expf(alF[ch*NSTATE + sub*4 + j]);
  const float Dch = DF[ch];

  const __hip_bfloat16* dp = delta + rb * DINNER + ch;
  const __hip_bfloat16* xp = xcH   + rb * DINNER + ch;
  const __hip_bfloat16* zp = zsH   + rb * DINNER + ch;

  f32x4 hv = *(const f32x4*)&hin[((size_t)(b*NCHUNK + c)*DINNER + ch)*NSTATE + sub*4];
  float h0=hv.x, h1=hv.y, h2=hv.z, h3=hv.w;

  float d0[GSTEP], x0[GSTEP], z0[GSTEP], d1[GSTEP], x1[GSTEP], z1[GSTEP];

#define PF(D_,X_,Z_,T0) \
  _Pragma("unroll") \
  for (int u = 0; u < GSTEP; ++u) { \
    D_[u] = bf2f(dp[(size_t)((T0)+u) * DINNER]); \
    X_[u] = bf2f(xp[(size_t)((T0)+u) * DINNER]); \
    Z_[u] = bf2f(zp[(size_t)((T0)+u) * DINNER]); \
  }
#define STEPS(D_,X_,Z_,T0) \
  _Pragma("unroll") \
  for (int u = 0; u < GSTEP; ++u) { \
    float d_ = D_[u]; \
    float du = d_ * X_[u]; \
    f32x4 B4 = *(const f32x4*)&BCs[((T0)+u)*32 + sub*4]; \
    f32x4 C4 = *(const f32x4*)&BCs[((T0)+u)*32 + 16 + sub*4]; \
    h0 = __expf(d_*negA[0])*h0 + du*B4.x; \
    h1 = __expf(d_*negA[1])*h1 + du*B4.y; \
    h2 = __expf(d_*negA[2])*h2 + du*B4.z; \
    h3 = __expf(d_*negA[3])*h3 + du*B4.w; \
    float p = h0*C4.x + h1*C4.y + h2*C4.z + h3*C4.w; \
    p += __shfl_xor(p, 1); \
    p += __shfl_xor(p, 2); \
    if (sub == 0) { \
      float y = (p + X_[u] * Dch) * Z_[u]; \
      yS[((T0)+u)*72 + chL] = f2bfbits(y); \
    } \
  }

  PF(d0, x0, z0, 0)
  for (int t0 = 0; t0 < CLEN; t0 += 2*GSTEP) {
    PF(d1, x1, z1, t0 + GSTEP)
    STEPS(d0, x0, z0, t0)
    if (t0 + 2*GSTEP < CLEN) { PF(d0, x0, z0, t0 + 2*GSTEP) }
    STEPS(d1, x1, z1, t0 + GSTEP)
  }
#undef PF
#undef STEPS

  // coalesced y flush: 256 threads x 16B = 4 KB slab (32 t x 64 ch)
  __syncthreads();
  {
    int t2 = tid >> 3, p2 = tid & 7;
    short8 v = *(const short8*)&yS[t2*72 + p2*8];
    *(short8*)(yH + (rb + t2)*DINNER + (cg << 6) + p2*8) = v;
  }
}

// ---------------------------------------------------------------------------
extern "C" void kernel_launch(void* const* d_in, const int* in_sizes, int n_in,
                              void* d_out, int out_size, void* d_ws, size_t ws_size,
                              hipStream_t stream)
{
  float* out = (float*)d_out;   // reference output dtype: float32
  char* ws = (char*)d_ws;
  const size_t MB = 1024*1024;

  // workspace layout (84 MB, liveness-aliased; ws_size = 256 MB)
  // scalar region offsets: VALIDATED R13 layout — do not renumber.
  int*            flag    = (int*)            (ws);
  float*          cwF     = (float*)          (ws + 1024);
  float*          cbF     = (float*)          (ws + 40*1024);
  float*          dtbF    = (float*)          (ws + 56*1024);
  float*          alF     = (float*)          (ws + 72*1024);
  float*          DF      = (float*)          (ws + 208*1024);
  float*          Sd      = (float*)          (ws + 256*1024);      // 512 KB (NCHUNK=32)
  __hip_bfloat16* xB      = (__hip_bfloat16*) (ws + 1*MB);          // 4 MB  (dead after G1)
  __hip_bfloat16* inpB    = (__hip_bfloat16*) (ws + 5*MB);          // 8 MB
  __hip_bfloat16* xiB     = (__hip_bfloat16*) (ws + 13*MB);         // 8 MB  (dead after conv)
  __hip_bfloat16* dltH    = (__hip_bfloat16*) (ws + 1*MB);          // 8 MB bf16 delta, aliases xB/inpB[:4MB]
  __hip_bfloat16* xprojB  = (__hip_bfloat16*) (ws + 21*MB);
  __hip_bfloat16* dtprojB = (__hip_bfloat16*) (ws + 21*MB + 512*1024);
  __hip_bfloat16* outpB   = (__hip_bfloat16*) (ws + 22*MB);         // 4 MB
  __hip_bfloat16* zsH     = (__hip_bfloat16*) (ws + 26*MB);         // 8 MB (bf16 silu(z))
  __hip_bfloat16* xcH     = (__hip_bfloat16*) (ws + 42*MB);         // 8 MB
  float*          xdbl    = (float*)          (ws + 50*MB);         // 768 KB
  __hip_bfloat16* yH      = (__hip_bfloat16*) (ws + 52*MB);         // 8 MB (live into out_proj)
  float*          Hc      = (float*)          (ws + 68*MB);         // 8 MB (NCHUNK=32)
  float*          hin     = (float*)          (ws + 76*MB);         // 8 MB -> top 84 MB
  // out_proj f32 partials (8 MB each), regions dead after emit_k:
  float*          q0      = (float*)          (ws + 1*MB);          // dltH (dead)
  float*          q1      = (float*)          (ws + 9*MB);          // xiB lo (dead)
  float*          q2      = (float*)          (ws + 26*MB);         // zsH (dead)
  float*          q3      = (float*)          (ws + 34*MB);         // free

  dim3 blk(256);
  dim3 gblk(512);

  // 0) sniff (1 tiny block) + vectorized canonicalize (+ xdbl zero-init)
  sniff_k<<<1, 64, 0, stream>>>((const unsigned short*)d_in[0], flag);
  CvtArgs ca = { d_in[0], d_in[1], d_in[2], d_in[3], d_in[4],
                 d_in[5], d_in[6], d_in[7], d_in[8], d_in[9],
                 xB, inpB, xprojB, dtprojB, outpB,
                 cwF, cbF, dtbF, alF, DF, xdbl, flag };
  convert_all_k<<<CVT_BLOCKS, blk, 0, stream>>>(ca);

  // 1) in_proj (2048 x 4096 x 1024): BK=128, XCD-swizzled, 512-thr blocks
  gemm64<4,2,1><<<dim3(4096/128, ROWS/128), gblk, 0, stream>>>(
      xB, inpB, ROWS, 2*DINNER, DMODEL, 0, nullptr, xiB, zsH, nullptr,
      nullptr, nullptr, nullptr, nullptr);

  // 2) xc = silu(depthwise_conv(xi) + b), x4 vectorized
  conv_silu_k<<<(ROWS*DINNER/4)/256, blk, 0, stream>>>(xiB, cwF, cbF, xcH);

  // 3) x_dbl (2048 x 96 x 2048): 16-way split-K (kchunk=128), atomic into xdbl
  gemm64<5,2,0><<<dim3(1, ROWS/128, KSPLIT), gblk, 0, stream>>>(
      xcH, xprojB, ROWS, 96, DINNER, DINNER/KSPLIT, xdbl, nullptr, nullptr, nullptr,
      nullptr, nullptr, nullptr, nullptr);

  // 4) delta = softplus(dt @ dt_proj^T + dt_b) (2048 x 2048 x 64):
  //    A staged directly from f32 xdbl (fused dt conversion), output bf16.
  gemm64<3,1,0><<<dim3(DINNER/128, ROWS/128), gblk, 0, stream>>>(
      (const __hip_bfloat16*)xdbl, dtprojB, ROWS, DINNER, DTRANK, 0,
      nullptr, dltH, nullptr, dtbF,
      nullptr, nullptr, nullptr, nullptr);

  // 5) chunked selective scan (NCHUNK=32) + fused combine -> bf16 yH
  stats_k<<<BATCH*NCHUNK*32, blk, 0, stream>>>(dltH, xcH, xdbl, alF, Hc, Sd);
  carry_k<<<(BATCH*DINNER*NSTATE)/256, blk, 0, stream>>>(Hc, Sd, alF, hin);
  emit_k<<<BATCH*NCHUNK*32, blk, 0, stream>>>(dltH, xcH, xdbl, zsH, alF, DF, hin, yH);

  // 6) out_proj (2048 x 1024 x 2048): BK=128, XCD-swizzled, 512-thr, split-K=4
  gemm64<6,2,1><<<dim3(DMODEL/128, ROWS/128, 4), gblk, 0, stream>>>(
      yH, outpB, ROWS, DMODEL, DINNER, DINNER/4, nullptr, nullptr, nullptr, nullptr,
      q0, q1, q2, q3);
  reduce_out_k<<<(ROWS*DMODEL/4)/256, blk, 0, stream>>>(q0, q1, q2, q3, out);
}